// Round 1
// baseline (518.395 us; speedup 1.0000x reference)
//
#include <hip/hip_runtime.h>

// Problem constants (B=8, G=1024, K=32, C=168, OUT_DIM=336)
#define NB 8
#define NG 1024
#define NK 32
#define NC 168
#define NOUTC 336
#define NX 44040192       // B*G*K*C
#define NXYZ 786432       // B*G*K*3
#define EPSV 1e-5f
#define PIO2 1.5707963267948966f
#define L2A_OVER_FD 0.17796043436f   // log2(1000)/56

#define NPART_X 1024
#define NPART_3 32
#define NPART (NPART_X + NPART_3)

// ---------------- Pass 1: partial sums for the two global stds ----------------
__global__ __launch_bounds__(256) void reduce_kernel(
    const float* __restrict__ knn_x, const float* __restrict__ lc_x,
    const float* __restrict__ knn_xyz, const float* __restrict__ lc_xyz,
    float4* __restrict__ part)
{
    float s = 0.f, q = 0.f, s3 = 0.f, q3 = 0.f;
    const int blk = blockIdx.x;
    const int tid = threadIdx.x;

    if (blk < NPART_X) {
        const float4* __restrict__ x4 = (const float4*)knn_x;
        const int n4 = NX / 4;                      // 11,010,048
        for (int i = blk * 256 + tid; i < n4; i += NPART_X * 256) {
            float4 v = x4[i];
            int bg  = i / 1344;                     // float4s per (b,g) row-block: 5376/4
            int c4  = i - bg * 1344;
            int r42 = c4 % 42;                      // float4s per c-row (168/4)
            float4 l = *(const float4*)(lc_x + (size_t)bg * NC + r42 * 4);
            float dx = v.x - l.x, dy = v.y - l.y, dz = v.z - l.z, dw = v.w - l.w;
            s += (dx + dy) + (dz + dw);
            q = fmaf(dx, dx, q); q = fmaf(dy, dy, q);
            q = fmaf(dz, dz, q); q = fmaf(dw, dw, q);
        }
    } else {
        for (int i = (blk - NPART_X) * 256 + tid; i < NXYZ; i += NPART_3 * 256) {
            float v = knn_xyz[i];
            int bg = i / 96;                        // K*3
            int j  = i % 3;
            float d = v - lc_xyz[bg * 3 + j];
            s3 += d;
            q3 = fmaf(d, d, q3);
        }
    }

    // block reduction (4 floats)
    for (int off = 32; off; off >>= 1) {
        s  += __shfl_down(s,  off);
        q  += __shfl_down(q,  off);
        s3 += __shfl_down(s3, off);
        q3 += __shfl_down(q3, off);
    }
    __shared__ float red[4][4];
    int wv = tid >> 6;
    if ((tid & 63) == 0) { red[wv][0] = s; red[wv][1] = q; red[wv][2] = s3; red[wv][3] = q3; }
    __syncthreads();
    if (tid == 0) {
        part[blk] = make_float4(red[0][0] + red[1][0] + red[2][0] + red[3][0],
                                red[0][1] + red[1][1] + red[2][1] + red[3][1],
                                red[0][2] + red[1][2] + red[2][2] + red[3][2],
                                red[0][3] + red[1][3] + red[2][3] + red[3][3]);
    }
}

// ---------------- Pass 2: finalize stds in double precision ----------------
__global__ __launch_bounds__(256) void finalize_kernel(
    const float4* __restrict__ part, float* __restrict__ stds)
{
    double s = 0.0, q = 0.0, s3 = 0.0, q3 = 0.0;
    for (int i = threadIdx.x; i < NPART; i += 256) {
        float4 p = part[i];
        s += p.x; q += p.y; s3 += p.z; q3 += p.w;
    }
    for (int off = 32; off; off >>= 1) {
        s  += __shfl_down(s,  off);
        q  += __shfl_down(q,  off);
        s3 += __shfl_down(s3, off);
        q3 += __shfl_down(q3, off);
    }
    __shared__ double red[4][4];
    int wv = threadIdx.x >> 6;
    if ((threadIdx.x & 63) == 0) { red[wv][0] = s; red[wv][1] = q; red[wv][2] = s3; red[wv][3] = q3; }
    __syncthreads();
    if (threadIdx.x == 0) {
        s  = red[0][0] + red[1][0] + red[2][0] + red[3][0];
        q  = red[0][1] + red[1][1] + red[2][1] + red[3][1];
        s3 = red[0][2] + red[1][2] + red[2][2] + red[3][2];
        q3 = red[0][3] + red[1][3] + red[2][3] + red[3][3];
        double varx = (q  - s  * s  / (double)NX)   / (double)(NX - 1);
        double var3 = (q3 - s3 * s3 / (double)NXYZ) / (double)(NXYZ - 1);
        stds[0] = 1.0f / ((float)sqrt(varx) + EPSV);   // 1/(std_x + eps)
        stds[1] = 1.0f / ((float)sqrt(var3) + EPSV);   // 1/(std_xyz + eps)
    }
}

// ---------------- Pass 3: main fused elementwise + transpose ----------------
// One block per (b,g). LDS-stage the 32x168 knn_x tile (row stride 169: reads
// with k across lanes hit all 32 banks), precompute per-channel constants once.
__global__ __launch_bounds__(256) void main_kernel(
    const float* __restrict__ lc_xyz, const float* __restrict__ lc_x,
    const float* __restrict__ knn_xyz, const float* __restrict__ knn_x,
    const float* __restrict__ stds, float* __restrict__ out)
{
    __shared__ float  s_x[NK * 169];     // raw knn_x tile, padded stride
    __shared__ float  s_emb[NK * 7];     // [k][{xn0,xn1,xn2,cr0,cr1,cr2,dot}]
    __shared__ float4 s_cc[NOUTC];       // {sin_scale, phase_off, pe_lc, lc_x[c]}
    __shared__ float  s_misc[8];         // inv_std_x, inv_std_xyz, lc0, lc1, lc2

    const int bg  = blockIdx.x;          // b*1024 + g
    const int b   = bg >> 10;
    const int g   = bg & 1023;
    const int tid = threadIdx.x;

    // ---- Phase A: scalars + stage knn_x tile ----
    if (tid < 2)      s_misc[tid] = stds[tid];
    else if (tid < 5) s_misc[tid] = lc_xyz[(size_t)bg * 3 + (tid - 2)];

    {
        const float4* __restrict__ src4 = (const float4*)(knn_x + (size_t)bg * (NK * NC));
        for (int i = tid; i < (NK * NC) / 4; i += 256) {   // 1344 float4s
            float4 v = src4[i];
            int kk = i / 42;
            int c4 = i - kk * 42;
            float* dst = s_x + kk * 169 + c4 * 4;
            dst[0] = v.x; dst[1] = v.y; dst[2] = v.z; dst[3] = v.w;
        }
    }
    __syncthreads();

    // ---- Phase B: per-k geometry (threads 0..31) + per-channel constants ----
    const float inv3 = s_misc[1];
    const float b0 = s_misc[2], b1 = s_misc[3], b2 = s_misc[4];
    if (tid < NK) {
        const float* kx = knn_xyz + (size_t)bg * (NK * 3) + tid * 3;
        float a0 = (kx[0] - b0) * inv3;
        float a1 = (kx[1] - b1) * inv3;
        float a2 = (kx[2] - b2) * inv3;
        float* e = s_emb + tid * 7;
        e[0] = a0; e[1] = a1; e[2] = a2;
        e[3] = a1 * b2 - a2 * b1;            // cross(knn_xyz_n, lc)
        e[4] = a2 * b0 - a0 * b2;
        e[5] = a0 * b1 - a1 * b0;
        e[6] = a0 * b0 + a1 * b1 + a2 * b2;  // dot
    }
    for (int c = tid; c < NOUTC; c += 256) {
        int dq = c / 112;                    // which xyz dim
        int r  = c - dq * 112;
        int sf = (r >= 56);                  // 0=sin, 1=cos
        int f  = r - (sf ? 56 : 0);
        float scale = 100.f * exp2f(-L2A_OVER_FD * (float)f);  // 100/alpha^(f/56)
        float off   = sf ? PIO2 : 0.f;       // cos(x) = sin(x + pi/2)
        float lcv   = (dq == 0) ? b0 : (dq == 1 ? b1 : b2);
        float pelc  = __sinf(fmaf(lcv, scale, off));
        float lx    = (c < NC) ? lc_x[(size_t)bg * NC + c] : 0.f;
        s_cc[c] = make_float4(scale, off, pelc, lx);
    }
    __syncthreads();

    // ---- Phase C: produce output [b, c, g, k] ----
    const float inv_sx = s_misc[0];
    const int   k      = tid & 31;
    const float xn0 = s_emb[k * 7 + 0];
    const float xn1 = s_emb[k * 7 + 1];
    const float xn2 = s_emb[k * 7 + 2];
    float* __restrict__ obase = out + (size_t)b * (NOUTC * NG * NK) + ((size_t)g << 5) + k;
    const float* __restrict__ sxk = s_x + k * 169;

    // channels 0..167: knn_x_n
    for (int idx = tid; idx < NC * NK; idx += 256) {
        int c = idx >> 5;
        float4 cc = s_cc[c];
        float w = (sxk[c] - cc.w) * inv_sx;
        float t = (c < 112) ? xn0 : xn1;
        float pe = __sinf(fmaf(t, cc.x, cc.y)) + cc.z;
        __builtin_nontemporal_store((w + pe) * pe, obase + ((size_t)c << 15));
    }
    // channels 168..335: tiled [xyz_n, cross, dot]
    for (int idx = tid; idx < NC * NK; idx += 256) {
        int c = NC + (idx >> 5);
        float4 cc = s_cc[c];
        float w = s_emb[k * 7 + (c % 7)];    // (c-168)%7 == c%7 since 168%7==0
        float t = (c < 224) ? xn1 : xn2;
        float pe = __sinf(fmaf(t, cc.x, cc.y)) + cc.z;
        __builtin_nontemporal_store((w + pe) * pe, obase + ((size_t)c << 15));
    }
}

extern "C" void kernel_launch(void* const* d_in, const int* in_sizes, int n_in,
                              void* d_out, int out_size, void* d_ws, size_t ws_size,
                              hipStream_t stream) {
    const float* lc_xyz  = (const float*)d_in[0];
    const float* lc_x    = (const float*)d_in[1];
    const float* knn_xyz = (const float*)d_in[2];
    const float* knn_x   = (const float*)d_in[3];
    float* out = (float*)d_out;

    float4* part = (float4*)d_ws;                                  // NPART*16 B = 16.9 KB
    float*  stds = (float*)((char*)d_ws + (size_t)NPART * sizeof(float4));

    reduce_kernel<<<NPART, 256, 0, stream>>>(knn_x, lc_x, knn_xyz, lc_xyz, part);
    finalize_kernel<<<1, 256, 0, stream>>>(part, stds);
    main_kernel<<<NB * NG, 256, 0, stream>>>(lc_xyz, lc_x, knn_xyz, knn_x, stds, out);
}